// Round 19
// baseline (3216.006 us; speedup 1.0000x reference)
//
#include <hip/hip_runtime.h>
#include <math.h>

// ---------------------------------------------------------------------------
// GSATSubgraph. Round 19: symmetric sim — compute upper-triangle tiles only
// (S[m][n] bit== S[n][m] by commutative per-product chain). Pass 1: r16
// in-register selection for rows. Pass 2 (off-diag): stage acc^T to LDS
// (union with dead As/Bs) + r14 4-wave selection for transposed rows.
// Candidate sets identical -> nbidx bit-identical. Rest unchanged from r18.
// ---------------------------------------------------------------------------

constexpr int C_  = 384;
constexpr int N_  = 784;
constexpr int B_  = 64;
constexpr int R_  = B_ * N_;        // 50176
constexpr int E_  = R_ * 9;         // 451584
constexpr long RC_ = (long)R_ * C_; // 19267584
constexpr int NT_ = 13;
constexpr int NC_ = NT_ * 9;        // 117
constexpr int NTRI_ = NT_ * (NT_ + 1) / 2;  // 91

typedef __bf16 bf16_t;
typedef __attribute__((ext_vector_type(8))) __bf16 bf16x8;
typedef __attribute__((ext_vector_type(4))) float f32x4;

__device__ __forceinline__ float gelu_tanh(float x) {
    float x3 = x * x * x;
    return 0.5f * x * (1.0f + tanhf(0.7978845608028654f * (x + 0.044715f * x3)));
}

// --------------------------------------------------------------------------
__global__ void prep_bn(const float* __restrict__ g1, const float* __restrict__ v1,
                        const float* __restrict__ gf1, const float* __restrict__ bf1,
                        const float* __restrict__ mf1, const float* __restrict__ vf1,
                        const float* __restrict__ gf2, const float* __restrict__ bf2,
                        const float* __restrict__ mf2, const float* __restrict__ vf2,
                        float* __restrict__ prep) {
    int i = blockIdx.x * 256 + threadIdx.x;
    float* pB1s = prep;
    float* pF1s = prep + 768;  float* pF1t = prep + 2304;
    float* pF2s = prep + 3840; float* pF2t = prep + 4224;
    if (i < 1536) {
        float s = gf1[i] * rsqrtf(vf1[i] + 1e-5f);
        pF1s[i] = s; pF1t[i] = bf1[i] - mf1[i] * s;
    }
    if (i < 384) {
        // FROZEN bn1 form: g * (1.0 / sqrt(v + 1e-5))
        const float inv = __fdiv_rn(1.0f, sqrtf(__fadd_rn(v1[i], 1e-5f)));
        pB1s[i] = __fmul_rn(g1[i], inv);
        float s = gf2[i] * rsqrtf(vf2[i] + 1e-5f);
        pF2s[i] = s; pF2t[i] = bf2[i] - mf2[i] * s;
    }
}

// --------------------------------------------------------------------------
__global__ void wconv_T(const float* __restrict__ W, bf16_t* __restrict__ WT,
                        int K, int N) {
    const int idx = blockIdx.x * 256 + threadIdx.x;
    if (idx >= N * K) return;
    const int n = idx / K, k = idx - n * K;
    WT[idx] = (bf16_t)W[(size_t)k * N + n];
}

// --------------------------------------------------------------------------
// FROZEN: fc1 (f32, seq-k FMA) + unfolded BN, no cross-op FMA
// --------------------------------------------------------------------------
__global__ __launch_bounds__(256) void fc1_gemm(
    const float* __restrict__ x, const float* __restrict__ fw,
    const float* __restrict__ fb, const float* __restrict__ s1,
    const float* __restrict__ m1, const float* __restrict__ bb1,
    float* __restrict__ out) {
    __shared__ float As[16][68];
    __shared__ float Bs[16][68];
    const int m0 = blockIdx.x * 64, o0 = blockIdx.y * 64;
    const int tid = threadIdx.x;
    const int tx = tid & 15, ty = tid >> 4;
    const int lm = tid & 63, kk = tid >> 6;
    const int gm = m0 + lm, bb = gm / N_, nn = gm - bb * N_;
    const float* xp = x + (size_t)bb * C_ * N_ + nn;
    const int lo = tid >> 2, lk = (tid & 3) * 4;
    const float* wp = fw + (size_t)(o0 + lo) * C_ + lk;
    float acc[4][4] = {};
    for (int k0 = 0; k0 < C_; k0 += 16) {
        float xa[4];
#pragma unroll
        for (int j = 0; j < 4; ++j) xa[j] = xp[(size_t)(k0 + kk * 4 + j) * N_];
        float4 wv = *(const float4*)(wp + k0);
#pragma unroll
        for (int j = 0; j < 4; ++j) As[kk * 4 + j][lm] = xa[j];
        Bs[lk + 0][lo] = wv.x; Bs[lk + 1][lo] = wv.y;
        Bs[lk + 2][lo] = wv.z; Bs[lk + 3][lo] = wv.w;
        __syncthreads();
#pragma unroll
        for (int k = 0; k < 16; ++k) {
            const float4 a4 = *(const float4*)&As[k][ty * 4];
            const float4 b4 = *(const float4*)&Bs[k][tx * 4];
            const float a[4] = {a4.x, a4.y, a4.z, a4.w};
            const float bq[4] = {b4.x, b4.y, b4.z, b4.w};
#pragma unroll
            for (int i = 0; i < 4; ++i)
#pragma unroll
                for (int j = 0; j < 4; ++j)
                    acc[i][j] = fmaf(a[i], bq[j], acc[i][j]);
        }
        __syncthreads();
    }
#pragma unroll
    for (int i = 0; i < 4; ++i) {
        const int m = m0 + ty * 4 + i;
        float* cp = out + (size_t)m * C_ + o0 + tx * 4;
        float4 o; float* ov = (float*)&o;
#pragma unroll
        for (int j = 0; j < 4; ++j) {
            const int n = o0 + tx * 4 + j;
            const float z = __fadd_rn(acc[i][j], fb[n]);
            const float u = __fsub_rn(z, m1[n]);
            ov[j] = __fadd_rn(__fmul_rn(u, s1[n]), bb1[n]);
        }
        *(float4*)cp = o;
    }
}

// --------------------------------------------------------------------------
// FROZEN: numpy-exact row norm (pairwise tree) + division
// --------------------------------------------------------------------------
__global__ __launch_bounds__(256) void rownorm_np(const float* __restrict__ h,
                                                  float* __restrict__ nm) {
    const int row = blockIdx.x * 256 + threadIdx.x;
    if (row >= R_) return;
    const float* p = h + (size_t)row * C_;
    float Bv[4];
#pragma unroll
    for (int b4 = 0; b4 < 4; ++b4) {
        const float* a = p + b4 * 96;
        float r[8];
#pragma unroll
        for (int j = 0; j < 8; ++j) r[j] = __fmul_rn(a[j], a[j]);
        for (int i = 8; i < 96; i += 8) {
#pragma unroll
            for (int j = 0; j < 8; ++j)
                r[j] = __fadd_rn(r[j], __fmul_rn(a[i + j], a[i + j]));
        }
        Bv[b4] = __fadd_rn(
            __fadd_rn(__fadd_rn(r[0], r[1]), __fadd_rn(r[2], r[3])),
            __fadd_rn(__fadd_rn(r[4], r[5]), __fadd_rn(r[6], r[7])));
    }
    const float s = __fadd_rn(__fadd_rn(Bv[0], Bv[1]), __fadd_rn(Bv[2], Bv[3]));
    nm[row] = fmaxf(sqrtf(s), 1e-12f);
}

__global__ __launch_bounds__(256) void l2div(float* __restrict__ h,
                                             const float* __restrict__ nm) {
    const int row = blockIdx.x * 4 + (threadIdx.x >> 6);
    const int lane = threadIdx.x & 63;
    const float d = nm[row];
    float* p = h + (size_t)row * C_;
#pragma unroll
    for (int t = 0; t < 6; ++t) p[lane + 64 * t] = __fdiv_rn(p[lane + 64 * t], d);
}

// --------------------------------------------------------------------------
// FROZEN math: FUSED sim (r14 scalar chained-muladd) on upper-tri tiles.
// Pass 1: in-register row selection (r16). Pass 2 (bx!=by): transpose via
// LDS (union with As/Bs) + r14 4-wave selection.
// --------------------------------------------------------------------------
__global__ __launch_bounds__(256) void sim_topk_np(
    const float* __restrict__ nf, float* __restrict__ cv, int* __restrict__ ci) {
    __shared__ float smem[4160];          // 16640 B: As|Bs during math, T after
    float (*As)[68] = (float(*)[68])smem;
    float (*Bs)[68] = (float(*)[68])(smem + 16 * 68);
    float (*T)[65]  = (float(*)[65])smem;
    // decode upper-triangle tile (bx, by), by >= bx
    int t = blockIdx.x, bx = 0;
    while (t >= NT_ - bx) { t -= NT_ - bx; ++bx; }
    const int by = bx + t;
    const int n0 = bx * 64, m0 = by * 64, b = blockIdx.z;
    const float* nfb = nf + (size_t)b * N_ * C_;
    const int tid = threadIdx.x;
    const int tx = tid & 15, ty = tid >> 4;
    const int lr = tid >> 2, lk = (tid & 3) * 4;
    const bool va = (n0 + lr) < N_;
    const bool vb = (m0 + lr) < N_;
    const float* pa = nfb + (size_t)(n0 + lr) * C_ + lk;
    const float* pb = nfb + (size_t)(m0 + lr) * C_ + lk;
    float acc[4][4][4] = {};
    for (int k0 = 0; k0 < C_; k0 += 16) {
        float4 av = {0.f, 0.f, 0.f, 0.f}, bv = {0.f, 0.f, 0.f, 0.f};
        if (va) av = *(const float4*)(pa + k0);
        if (vb) bv = *(const float4*)(pb + k0);
        As[lk + 0][lr] = av.x; As[lk + 1][lr] = av.y;
        As[lk + 2][lr] = av.z; As[lk + 3][lr] = av.w;
        Bs[lk + 0][lr] = bv.x; Bs[lk + 1][lr] = bv.y;
        Bs[lk + 2][lr] = bv.z; Bs[lk + 3][lr] = bv.w;
        __syncthreads();
#pragma unroll
        for (int grp = 0; grp < 4; ++grp) {
            const int kb = (3 - grp) * 4;
#pragma unroll
            for (int kl = 0; kl < 4; ++kl) {
                const int k = kb + kl;
                const float4 a4 = *(const float4*)&As[k][ty * 4];
                const float4 b4 = *(const float4*)&Bs[k][tx * 4];
                const float a[4] = {a4.x, a4.y, a4.z, a4.w};
                const float bq[4] = {b4.x, b4.y, b4.z, b4.w};
#pragma unroll
                for (int i = 0; i < 4; ++i)
#pragma unroll
                    for (int j = 0; j < 4; ++j)
                        acc[i][j][kl] = __fadd_rn(__fmul_rn(a[i], bq[j]),
                                                  acc[i][j][kl]);
            }
        }
        __syncthreads();
    }
    // finalize values (hadd tree + diag), keep in fin[i][j]
    float fin[4][4];
#pragma unroll
    for (int i = 0; i < 4; ++i) {
        const int n = n0 + ty * 4 + i;
#pragma unroll
        for (int j = 0; j < 4; ++j) {
            const float* r = acc[i][j];
            float v = __fadd_rn(__fadd_rn(r[0], r[1]), __fadd_rn(r[2], r[3]));
            const int m = m0 + tx * 4 + j;
            if (n == m) v = __fsub_rn(v, 4.0f);
            if (m >= N_) v = -3.0e38f;
            fin[i][j] = v;
        }
    }
    // ---- pass 1: in-register selection for rows n (bx band), tile by ----
#pragma unroll
    for (int i = 0; i < 4; ++i) {
        const int n = n0 + ty * 4 + i;
        float sv[4]; int si[4];
#pragma unroll
        for (int j = 0; j < 4; ++j) { sv[j] = fin[i][j]; si[j] = m0 + tx * 4 + j; }
#pragma unroll
        for (int s = 0; s < 5; ++s) {
            const int pa_[5] = {0, 2, 0, 1, 1};
            const int pb_[5] = {1, 3, 2, 3, 2};
            const int a_ = pa_[s], b_ = pb_[s];
            const bool sw = (sv[b_] > sv[a_]) || (sv[b_] == sv[a_] && si[b_] < si[a_]);
            const float tv = sw ? sv[b_] : sv[a_]; const int ti = sw ? si[b_] : si[a_];
            sv[b_] = sw ? sv[a_] : sv[b_]; si[b_] = sw ? si[a_] : si[b_];
            sv[a_] = tv; si[a_] = ti;
        }
#pragma unroll
        for (int it = 0; it < 9; ++it) {
            float bv2 = sv[0]; int bi = si[0];
#pragma unroll
            for (int mk = 1; mk <= 8; mk <<= 1) {
                const float ov = __shfl_xor(bv2, mk, 64);
                const int  oi = __shfl_xor(bi, mk, 64);
                if (ov > bv2 || (ov == bv2 && oi < bi)) { bv2 = ov; bi = oi; }
            }
            if (si[0] == bi) {
                sv[0] = sv[1]; si[0] = si[1];
                sv[1] = sv[2]; si[1] = si[2];
                sv[2] = sv[3]; si[2] = si[3];
                sv[3] = -3.0e38f; si[3] = 0x7fffffff;
            }
            if (tx == 0 && n < N_) {
                const size_t o = ((size_t)b * N_ + n) * NC_ + by * 9 + it;
                cv[o] = bv2; ci[o] = bi;
            }
        }
    }
    if (bx == by) return;
    // ---- pass 2: transposed rows m (by band), tile bx ----
    __syncthreads();   // As/Bs dead; reuse as T
#pragma unroll
    for (int i = 0; i < 4; ++i)
#pragma unroll
        for (int j = 0; j < 4; ++j)
            T[tx * 4 + j][ty * 4 + i] = fin[i][j];
    __syncthreads();
    const int wv = tid >> 6, lane = tid & 63;
    for (int rr = 0; rr < 16; ++rr) {
        const int r = wv * 16 + rr;          // local m index
        const int m = m0 + r;
        if (m >= N_) continue;               // wave-uniform
        float val = T[r][lane];              // cols n = n0+lane, all valid (bx<12)
        int idx = n0 + lane;
#pragma unroll
        for (int it = 0; it < 9; ++it) {
            float bv2 = val; int bi = idx;
#pragma unroll
            for (int off = 32; off; off >>= 1) {
                const float ov = __shfl_xor(bv2, off, 64);
                const int  oi = __shfl_xor(bi, off, 64);
                if (ov > bv2 || (ov == bv2 && oi < bi)) { bv2 = ov; bi = oi; }
            }
            if (idx == bi) val = -3.0e38f;
            if (lane == 0) {
                const size_t o = ((size_t)b * N_ + m) * NC_ + bx * 9 + it;
                cv[o] = bv2; ci[o] = bi;
            }
        }
    }
}

// --------------------------------------------------------------------------
__global__ __launch_bounds__(256) void merge_topk(
    const float* __restrict__ cv, const int* __restrict__ ci,
    int* __restrict__ nbidx) {
    const int row = blockIdx.x * 4 + (threadIdx.x >> 6);
    const int lane = threadIdx.x & 63;
    const size_t base = (size_t)row * NC_;
    float v0 = cv[base + lane]; int i0 = ci[base + lane];
    float v1 = -3.0e38f; int i1 = 0x7fffffff;
    if (lane + 64 < NC_) { v1 = cv[base + 64 + lane]; i1 = ci[base + 64 + lane]; }
#pragma unroll
    for (int it = 0; it < 9; ++it) {
        float bv = v0; int bi = i0;
        if (v1 > bv || (v1 == bv && i1 < bi)) { bv = v1; bi = i1; }
#pragma unroll
        for (int off = 32; off; off >>= 1) {
            const float ov = __shfl_xor(bv, off, 64);
            const int  oi = __shfl_xor(bi, off, 64);
            if (ov > bv || (ov == bv && oi < bi)) { bv = ov; bi = oi; }
        }
        if (i0 == bi) v0 = -3.0e38f;
        if (i1 == bi) v1 = -3.0e38f;
        if (lane == 0) nbidx[(size_t)row * 9 + it] = bi;
    }
}

// --------------------------------------------------------------------------
__global__ void gin_gather(const float* __restrict__ nf, const int* __restrict__ nbidx,
                           const float* __restrict__ w, const float* __restrict__ epsp,
                           bf16_t* __restrict__ outbf) {
    const int node = blockIdx.x;
    const int c = threadIdx.x;
    const int b = node / N_;
    const float* nfb = nf + (size_t)b * N_ * C_;
    const int nl = node - b * N_;
    float acc = (1.0f + epsp[0]) * nfb[(size_t)nl * C_ + c];
#pragma unroll
    for (int j = 0; j < 9; ++j) {
        const int ij = nbidx[(size_t)node * 9 + j];
        const float wj = w ? w[(size_t)node * 9 + j] : 1.0f;
        acc += wj * nfb[(size_t)ij * C_ + c];
    }
    outbf[(size_t)node * C_ + c] = (bf16_t)acc;
}

// --------------------------------------------------------------------------
// bf16 MFMA GEMM, 128-row tiles (r18)
// --------------------------------------------------------------------------
template <int ACT, bool ACCUM, bool WF32, bool WBF>
__global__ __launch_bounds__(256) void bgemm(
    const bf16_t* __restrict__ A, int lda, int ka,
    const bf16_t* __restrict__ WT, int ldwt,
    const float* __restrict__ bias, const float* __restrict__ bns,
    const float* __restrict__ bnt,
    float* __restrict__ Cf, bf16_t* __restrict__ Cb, int ldc) {
    const int wave = threadIdx.x >> 6, lane = threadIdx.x & 63;
    const int m0 = blockIdx.x * 128 + wave * 32;
    const int n0 = blockIdx.y * 64;
    const int csub = lane & 15;
    const int kslot = (lane >> 4) * 8;
    const bf16_t* ap0 = A + (size_t)(m0 + csub) * lda + kslot;
    const bf16_t* ap1 = A + (size_t)(m0 + 16 + csub) * lda + kslot;
    f32x4 acc[2][4];
#pragma unroll
    for (int mi = 0; mi < 2; ++mi)
#pragma unroll
        for (int c4 = 0; c4 < 4; ++c4) acc[mi][c4] = (f32x4){0.f, 0.f, 0.f, 0.f};
    const bf16_t* bp[4];
#pragma unroll
    for (int c4 = 0; c4 < 4; ++c4)
        bp[c4] = WT + (size_t)(n0 + c4 * 16 + csub) * ldwt + kslot;
    for (int k0 = 0; k0 < ka; k0 += 32) {
        const bf16x8 a0 = *(const bf16x8*)(ap0 + k0);
        const bf16x8 a1 = *(const bf16x8*)(ap1 + k0);
#pragma unroll
        for (int c4 = 0; c4 < 4; ++c4) {
            const bf16x8 bfrag = *(const bf16x8*)(bp[c4] + k0);
            acc[0][c4] = __builtin_amdgcn_mfma_f32_16x16x32_bf16(a0, bfrag, acc[0][c4], 0, 0, 0);
            acc[1][c4] = __builtin_amdgcn_mfma_f32_16x16x32_bf16(a1, bfrag, acc[1][c4], 0, 0, 0);
        }
    }
#pragma unroll
    for (int mi = 0; mi < 2; ++mi) {
        const int rbase = m0 + mi * 16 + (lane >> 4) * 4;
#pragma unroll
        for (int c4 = 0; c4 < 4; ++c4) {
            const int gcol = n0 + c4 * 16 + csub;
#pragma unroll
            for (int r = 0; r < 4; ++r) {
                const int grow = rbase + r;
                float z = acc[mi][c4][r];
                if (bias) z += bias[gcol];
                if (bns)  z = z * bns[gcol] + bnt[gcol];
                if (ACT == 1) z = fmaxf(z, 0.0f);
                if (ACT == 2) z = gelu_tanh(z);
                if (ACCUM) z += Cf[(size_t)grow * ldc + gcol];
                if (WF32) Cf[(size_t)grow * ldc + gcol] = z;
                if (WBF)  Cb[(size_t)grow * ldc + gcol] = (bf16_t)z;
            }
        }
    }
}

// --------------------------------------------------------------------------
// edge attention: one WAVE per node, eA read once (r18)
// --------------------------------------------------------------------------
__global__ __launch_bounds__(256) void edge_att_node(
    const float* __restrict__ eA, const float* __restrict__ eB,
    const int* __restrict__ nbidx, const float* __restrict__ w2,
    const float* __restrict__ b2p, float* __restrict__ out) {
    const int node = blockIdx.x * 4 + (threadIdx.x >> 6);
    const int lane = threadIdx.x & 63;
    const int b = node / N_;
    const float* pa = eA + (size_t)node * C_;
    const float* ebb = eB + (size_t)b * N_ * C_;
    int idx[9];
#pragma unroll
    for (int j = 0; j < 9; ++j) idx[j] = nbidx[(size_t)node * 9 + j];
    float s[9];
#pragma unroll
    for (int j = 0; j < 9; ++j) s[j] = 0.f;
#pragma unroll
    for (int t = 0; t < 6; ++t) {
        const int c = lane + 64 * t;
        const float a = pa[c];
        const float w = w2[c];
#pragma unroll
        for (int j = 0; j < 9; ++j)
            s[j] += fmaxf(a + ebb[(size_t)idx[j] * C_ + c], 0.f) * w;
    }
#pragma unroll
    for (int j = 0; j < 9; ++j)
#pragma unroll
        for (int off = 32; off; off >>= 1) s[j] += __shfl_xor(s[j], off, 64);
    if (lane < 9)
        out[(size_t)node * 9 + lane] =
            1.0f / (1.0f + expf(-(s[lane] + b2p[0])));
}

// --------------------------------------------------------------------------
__global__ __launch_bounds__(256) void ffn_final(
    const float* __restrict__ acc, const float* __restrict__ ne,
    const float* __restrict__ b2, const float* __restrict__ s2,
    const float* __restrict__ t2, float* __restrict__ out) {
    __shared__ float T[32][33];
    const int bb = blockIdx.z;
    const int n0 = blockIdx.x * 32, c0 = blockIdx.y * 32;
    const int tx = threadIdx.x, ty = threadIdx.y;
#pragma unroll
    for (int ii = 0; ii < 4; ++ii) {
        const int nl = ty + 8 * ii;
        const int n = n0 + nl, c = c0 + tx;
        float z = 0.f;
        if (n < N_) {
            const size_t o = ((size_t)bb * N_ + n) * C_ + c;
            z = (acc[o] + b2[c]) * s2[c] + t2[c] + ne[o];
        }
        T[nl][tx] = z;
    }
    __syncthreads();
#pragma unroll
    for (int ii = 0; ii < 4; ++ii) {
        const int cl = ty + 8 * ii;
        const int n = n0 + tx;
        if (n < N_) out[((size_t)bb * C_ + c0 + cl) * N_ + n] = T[tx][cl];
    }
}

// --------------------------------------------------------------------------
extern "C" void kernel_launch(void* const* d_in, const int* in_sizes, int n_in,
                              void* d_out, int out_size, void* d_ws, size_t ws_size,
                              hipStream_t stream) {
    (void)in_sizes; (void)n_in; (void)out_size; (void)ws_size;
    const float* x      = (const float*)d_in[0];
    const float* fc1_w  = (const float*)d_in[2];
    const float* fc1_b  = (const float*)d_in[3];
    const float* bn1_g  = (const float*)d_in[4];
    const float* bn1_b  = (const float*)d_in[5];
    const float* bn1_m  = (const float*)d_in[6];
    const float* bn1_v  = (const float*)d_in[7];
    const float* gineps = (const float*)d_in[8];
    const float* gin_w1 = (const float*)d_in[9];
    const float* gin_b1 = (const float*)d_in[10];
    const float* gin_w2 = (const float*)d_in[11];
    const float* gin_b2 = (const float*)d_in[12];
    const float* att_w1 = (const float*)d_in[13];
    const float* att_b1 = (const float*)d_in[14];
    const float* att_w2 = (const float*)d_in[15];
    const float* att_b2 = (const float*)d_in[16];
    const float* ffn_w1 = (const float*)d_in[17];
    const float* ffn_b1 = (const float*)d_in[18];
    const float* fbn1_g = (const float*)d_in[19];
    const float* fbn1_b = (const float*)d_in[20];
    const float* fbn1_m = (const float*)d_in[21];
    const float* fbn1_v = (const float*)d_in[22];
    const float* ffn_w2 = (const float*)d_in[23];
    const float* ffn_b2 = (const float*)d_in[24];
    const float* fbn2_g = (const float*)d_in[25];
    const float* fbn2_b = (const float*)d_in[26];
    const float* fbn2_m = (const float*)d_in[27];
    const float* fbn2_v = (const float*)d_in[28];

    float* outp = (float*)d_out;

    // ws pool: [P0 RC][P1 RC][P2 RC][nbidx E int][prep 4608][norms R_][WT bf16]
    float* P0 = (float*)d_ws;
    float* P1 = P0 + RC_;
    float* P2 = P0 + 2 * RC_;                 // NF lives here
    int*   nbidx = (int*)(P0 + 3 * RC_);
    float* prep  = (float*)(nbidx + E_);
    float* norms = prep + 4608;
    bf16_t* gw1T = (bf16_t*)(norms + R_);     // [768][384]
    bf16_t* gw2T = gw1T + 768 * 384;          // [384][768]
    bf16_t* fw1T = gw2T + 384 * 768;          // [1536][384]
    bf16_t* fw2T = fw1T + 1536 * 384;         // [384][1536]
    bf16_t* aw1Ttop = fw2T + 384 * 1536;      // [384][384]
    bf16_t* aw1Tbot = aw1Ttop + 384 * 384;    // [384][384]
    float* cv = P0;                           // R*117 floats
    int*   ci = (int*)(cv + (size_t)R_ * NC_);
    float* EMB = outp + E_;                   // out-1 region as scratch
    const float* pB1s = prep;
    const float* pF1s = prep + 768,  *pF1t = prep + 2304;
    const float* pF2s = prep + 3840, *pF2t = prep + 4224;

    const dim3 gg6(784, 6), gb6(392, 6), gb12(392, 12);

    prep_bn<<<6, 256, 0, stream>>>(bn1_g, bn1_v,
                                   fbn1_g, fbn1_b, fbn1_m, fbn1_v,
                                   fbn2_g, fbn2_b, fbn2_m, fbn2_v, prep);
    wconv_T<<<(768 * 384 + 255) / 256, 256, 0, stream>>>(gin_w1, gw1T, 384, 768);
    wconv_T<<<(384 * 768 + 255) / 256, 256, 0, stream>>>(gin_w2, gw2T, 768, 384);
    wconv_T<<<(1536 * 384 + 255) / 256, 256, 0, stream>>>(ffn_w1, fw1T, 384, 1536);
    wconv_T<<<(384 * 1536 + 255) / 256, 256, 0, stream>>>(ffn_w2, fw2T, 1536, 384);
    wconv_T<<<(384 * 384 + 255) / 256, 256, 0, stream>>>(att_w1, aw1Ttop, 384, 384);
    wconv_T<<<(384 * 384 + 255) / 256, 256, 0, stream>>>(att_w1 + (size_t)384 * 384,
                                                         aw1Tbot, 384, 384);

    // FROZEN nbidx chain: nf -> P2
    fc1_gemm<<<gg6, 256, 0, stream>>>(x, fc1_w, fc1_b, pB1s, bn1_m, bn1_b, P2);
    rownorm_np<<<R_ / 256, 256, 0, stream>>>(P2, norms);
    l2div<<<R_ / 4, 256, 0, stream>>>(P2, norms);
    sim_topk_np<<<dim3(NTRI_, 1, B_), 256, 0, stream>>>(P2, cv, ci);
    merge_topk<<<R_ / 4, 256, 0, stream>>>(cv, ci, nbidx);

    // GIN1 (bf16): h1bf -> P0 lo (cv/ci dead); midbf -> P1; embbf -> P0 hi
    bf16_t* h1bf  = (bf16_t*)P0;
    bf16_t* midbf = (bf16_t*)P1;
    bf16_t* embbf = (bf16_t*)(P0 + RC_ / 2);
    gin_gather<<<R_, 384, 0, stream>>>(P2, nbidx, nullptr, gineps, h1bf);
    bgemm<1, false, false, true><<<gb12, 256, 0, stream>>>(
        h1bf, 384, 384, gw1T, 384, gin_b1, nullptr, nullptr,
        nullptr, midbf, 768);
    bgemm<0, false, false, true><<<gb6, 256, 0, stream>>>(
        midbf, 768, 768, gw2T, 768, gin_b2, nullptr, nullptr,
        nullptr, embbf, 384);

    // attention (bf16 gemms, f32 outputs): embA -> P1 (midbf dead), embB -> EMB
    bgemm<0, false, true, false><<<gb6, 256, 0, stream>>>(
        embbf, 384, 384, aw1Ttop, 384, att_b1, nullptr, nullptr,
        P1, nullptr, 384);
    bgemm<0, false, true, false><<<gb6, 256, 0, stream>>>(
        embbf, 384, 384, aw1Tbot, 384, nullptr, nullptr, nullptr,
        EMB, nullptr, 384);
    edge_att_node<<<R_ / 4, 256, 0, stream>>>(P1, EMB, nbidx, att_w2, att_b2, outp);

    // GIN2 (bf16): h2bf -> P0 lo; mid -> P1; ne f32 -> P0, nebf -> EMB
    bf16_t* h2bf = (bf16_t*)P0;
    bf16_t* nebf = (bf16_t*)EMB;
    gin_gather<<<R_, 384, 0, stream>>>(P2, nbidx, outp, gineps, h2bf);
    bgemm<1, false, false, true><<<gb12, 256, 0, stream>>>(
        h2bf, 384, 384, gw1T, 384, gin_b1, nullptr, nullptr,
        nullptr, (bf16_t*)P1, 768);
    bgemm<0, false, true, true><<<gb6, 256, 0, stream>>>(
        (bf16_t*)P1, 768, 768, gw2T, 768, gin_b2, nullptr, nullptr,
        P0, nebf, 384);

    // FFN (bf16, 2 K-chunks of 768): ybf -> P1; acc -> P2 (NF dead)
    bf16_t* ybf = (bf16_t*)P1;
    for (int g = 0; g < 2; ++g) {
        bgemm<2, false, false, true><<<gb12, 256, 0, stream>>>(
            nebf, 384, 384, fw1T + (size_t)g * 768 * 384, 384,
            ffn_b1 + g * 768, pF1s + g * 768, pF1t + g * 768,
            nullptr, ybf, 768);
        if (g == 0)
            bgemm<0, false, true, false><<<gb6, 256, 0, stream>>>(
                ybf, 768, 768, fw2T + (size_t)g * 768, 1536,
                nullptr, nullptr, nullptr, P2, nullptr, 384);
        else
            bgemm<0, true, true, false><<<gb6, 256, 0, stream>>>(
                ybf, 768, 768, fw2T + (size_t)g * 768, 1536,
                nullptr, nullptr, nullptr, P2, nullptr, 384);
    }

    // BN2 + residual + transpose (acc = P2, ne = P0) -> out-1
    ffn_final<<<dim3(25, 12, 64), dim3(32, 8), 0, stream>>>(P2, P0, ffn_b2,
                                                            pF2s, pF2t, outp + E_);
}

// Round 20
// 2887.751 us; speedup vs baseline: 1.1137x; 1.1137x over previous
//
#include <hip/hip_runtime.h>
#include <math.h>

// ---------------------------------------------------------------------------
// GSATSubgraph. Round 20: revert sim_topk to r18 (triangle harvest regressed
// occupancy); fc1 retiled 128x64 (bit-exact: per-output chain unchanged).
// Everything else r18-identical. FROZEN nbidx chain semantics preserved.
// ---------------------------------------------------------------------------

constexpr int C_  = 384;
constexpr int N_  = 784;
constexpr int B_  = 64;
constexpr int R_  = B_ * N_;        // 50176
constexpr int E_  = R_ * 9;         // 451584
constexpr long RC_ = (long)R_ * C_; // 19267584
constexpr int NT_ = 13;
constexpr int NC_ = NT_ * 9;        // 117

typedef __bf16 bf16_t;
typedef __attribute__((ext_vector_type(8))) __bf16 bf16x8;
typedef __attribute__((ext_vector_type(4))) float f32x4;

__device__ __forceinline__ float gelu_tanh(float x) {
    float x3 = x * x * x;
    return 0.5f * x * (1.0f + tanhf(0.7978845608028654f * (x + 0.044715f * x3)));
}

// --------------------------------------------------------------------------
__global__ void prep_bn(const float* __restrict__ g1, const float* __restrict__ v1,
                        const float* __restrict__ gf1, const float* __restrict__ bf1,
                        const float* __restrict__ mf1, const float* __restrict__ vf1,
                        const float* __restrict__ gf2, const float* __restrict__ bf2,
                        const float* __restrict__ mf2, const float* __restrict__ vf2,
                        float* __restrict__ prep) {
    int i = blockIdx.x * 256 + threadIdx.x;
    float* pB1s = prep;
    float* pF1s = prep + 768;  float* pF1t = prep + 2304;
    float* pF2s = prep + 3840; float* pF2t = prep + 4224;
    if (i < 1536) {
        float s = gf1[i] * rsqrtf(vf1[i] + 1e-5f);
        pF1s[i] = s; pF1t[i] = bf1[i] - mf1[i] * s;
    }
    if (i < 384) {
        // FROZEN bn1 form: g * (1.0 / sqrt(v + 1e-5))
        const float inv = __fdiv_rn(1.0f, sqrtf(__fadd_rn(v1[i], 1e-5f)));
        pB1s[i] = __fmul_rn(g1[i], inv);
        float s = gf2[i] * rsqrtf(vf2[i] + 1e-5f);
        pF2s[i] = s; pF2t[i] = bf2[i] - mf2[i] * s;
    }
}

// --------------------------------------------------------------------------
__global__ void wconv_T(const float* __restrict__ W, bf16_t* __restrict__ WT,
                        int K, int N) {
    const int idx = blockIdx.x * 256 + threadIdx.x;
    if (idx >= N * K) return;
    const int n = idx / K, k = idx - n * K;
    WT[idx] = (bf16_t)W[(size_t)k * N + n];
}

// --------------------------------------------------------------------------
// FROZEN math: fc1 (f32, seq-k FMA) + unfolded BN. 128x64 tile (bit-exact:
// per-output ascending-k fmaf chain and epilogue ops unchanged vs r14).
// --------------------------------------------------------------------------
__global__ __launch_bounds__(256) void fc1_gemm(
    const float* __restrict__ x, const float* __restrict__ fw,
    const float* __restrict__ fb, const float* __restrict__ s1,
    const float* __restrict__ m1, const float* __restrict__ bb1,
    float* __restrict__ out) {
    __shared__ float As[16][136];
    __shared__ float Bs[16][68];
    const int m0 = blockIdx.x * 128, o0 = blockIdx.y * 64;
    const int tid = threadIdx.x;
    const int tx = tid & 15, ty = tid >> 4;
    // A loader: 128 rows, 2 k-octets
    const int lm = tid & 127, kk2 = tid >> 7;
    const int gm = m0 + lm, bb = gm / N_, nn = gm - bb * N_;
    const float* xp = x + (size_t)bb * C_ * N_ + nn;
    // B loader: fw[o][c] row-major, float4 along c
    const int lo = tid >> 2, lk = (tid & 3) * 4;
    const float* wp = fw + (size_t)(o0 + lo) * C_ + lk;
    float acc[8][4] = {};
    for (int k0 = 0; k0 < C_; k0 += 16) {
        float xa[8];
#pragma unroll
        for (int j = 0; j < 8; ++j) xa[j] = xp[(size_t)(k0 + kk2 * 8 + j) * N_];
        float4 wv = *(const float4*)(wp + k0);
#pragma unroll
        for (int j = 0; j < 8; ++j) As[kk2 * 8 + j][lm] = xa[j];
        Bs[lk + 0][lo] = wv.x; Bs[lk + 1][lo] = wv.y;
        Bs[lk + 2][lo] = wv.z; Bs[lk + 3][lo] = wv.w;
        __syncthreads();
#pragma unroll
        for (int k = 0; k < 16; ++k) {
            const float4 a40 = *(const float4*)&As[k][ty * 8];
            const float4 a41 = *(const float4*)&As[k][ty * 8 + 4];
            const float4 b4 = *(const float4*)&Bs[k][tx * 4];
            const float a[8] = {a40.x, a40.y, a40.z, a40.w,
                                a41.x, a41.y, a41.z, a41.w};
            const float bq[4] = {b4.x, b4.y, b4.z, b4.w};
#pragma unroll
            for (int i = 0; i < 8; ++i)
#pragma unroll
                for (int j = 0; j < 4; ++j)
                    acc[i][j] = fmaf(a[i], bq[j], acc[i][j]);
        }
        __syncthreads();
    }
#pragma unroll
    for (int i = 0; i < 8; ++i) {
        const int m = m0 + ty * 8 + i;
        float* cp = out + (size_t)m * C_ + o0 + tx * 4;
        float4 o; float* ov = (float*)&o;
#pragma unroll
        for (int j = 0; j < 4; ++j) {
            const int n = o0 + tx * 4 + j;
            const float z = __fadd_rn(acc[i][j], fb[n]);
            const float u = __fsub_rn(z, m1[n]);
            ov[j] = __fadd_rn(__fmul_rn(u, s1[n]), bb1[n]);
        }
        *(float4*)cp = o;
    }
}

// --------------------------------------------------------------------------
// FROZEN: numpy-exact row norm (pairwise tree) + division
// --------------------------------------------------------------------------
__global__ __launch_bounds__(256) void rownorm_np(const float* __restrict__ h,
                                                  float* __restrict__ nm) {
    const int row = blockIdx.x * 256 + threadIdx.x;
    if (row >= R_) return;
    const float* p = h + (size_t)row * C_;
    float Bv[4];
#pragma unroll
    for (int b4 = 0; b4 < 4; ++b4) {
        const float* a = p + b4 * 96;
        float r[8];
#pragma unroll
        for (int j = 0; j < 8; ++j) r[j] = __fmul_rn(a[j], a[j]);
        for (int i = 8; i < 96; i += 8) {
#pragma unroll
            for (int j = 0; j < 8; ++j)
                r[j] = __fadd_rn(r[j], __fmul_rn(a[i + j], a[i + j]));
        }
        Bv[b4] = __fadd_rn(
            __fadd_rn(__fadd_rn(r[0], r[1]), __fadd_rn(r[2], r[3])),
            __fadd_rn(__fadd_rn(r[4], r[5]), __fadd_rn(r[6], r[7])));
    }
    const float s = __fadd_rn(__fadd_rn(Bv[0], Bv[1]), __fadd_rn(Bv[2], Bv[3]));
    nm[row] = fmaxf(sqrtf(s), 1e-12f);
}

__global__ __launch_bounds__(256) void l2div(float* __restrict__ h,
                                             const float* __restrict__ nm) {
    const int row = blockIdx.x * 4 + (threadIdx.x >> 6);
    const int lane = threadIdx.x & 63;
    const float d = nm[row];
    float* p = h + (size_t)row * C_;
#pragma unroll
    for (int t = 0; t < 6; ++t) p[lane + 64 * t] = __fdiv_rn(p[lane + 64 * t], d);
}

// --------------------------------------------------------------------------
// FROZEN (r18 verbatim): FUSED sim (r14 scalar chained-muladd) +
// in-register per-row top-9 via 16-lane tournament.
// --------------------------------------------------------------------------
__global__ __launch_bounds__(256) void sim_topk_np(
    const float* __restrict__ nf, float* __restrict__ cv, int* __restrict__ ci) {
    __shared__ float As[16][68];
    __shared__ float Bs[16][68];
    const int n0 = blockIdx.x * 64, m0 = blockIdx.y * 64, b = blockIdx.z;
    const float* nfb = nf + (size_t)b * N_ * C_;
    const int tid = threadIdx.x;
    const int tx = tid & 15, ty = tid >> 4;
    const int lr = tid >> 2, lk = (tid & 3) * 4;
    const bool va = (n0 + lr) < N_;
    const bool vb = (m0 + lr) < N_;
    const float* pa = nfb + (size_t)(n0 + lr) * C_ + lk;
    const float* pb = nfb + (size_t)(m0 + lr) * C_ + lk;
    float acc[4][4][4] = {};
    for (int k0 = 0; k0 < C_; k0 += 16) {
        float4 av = {0.f, 0.f, 0.f, 0.f}, bv = {0.f, 0.f, 0.f, 0.f};
        if (va) av = *(const float4*)(pa + k0);
        if (vb) bv = *(const float4*)(pb + k0);
        As[lk + 0][lr] = av.x; As[lk + 1][lr] = av.y;
        As[lk + 2][lr] = av.z; As[lk + 3][lr] = av.w;
        Bs[lk + 0][lr] = bv.x; Bs[lk + 1][lr] = bv.y;
        Bs[lk + 2][lr] = bv.z; Bs[lk + 3][lr] = bv.w;
        __syncthreads();
#pragma unroll
        for (int grp = 0; grp < 4; ++grp) {
            const int kb = (3 - grp) * 4;
#pragma unroll
            for (int kl = 0; kl < 4; ++kl) {
                const int k = kb + kl;
                const float4 a4 = *(const float4*)&As[k][ty * 4];
                const float4 b4 = *(const float4*)&Bs[k][tx * 4];
                const float a[4] = {a4.x, a4.y, a4.z, a4.w};
                const float bq[4] = {b4.x, b4.y, b4.z, b4.w};
#pragma unroll
                for (int i = 0; i < 4; ++i)
#pragma unroll
                    for (int j = 0; j < 4; ++j)
                        acc[i][j][kl] = __fadd_rn(__fmul_rn(a[i], bq[j]),
                                                  acc[i][j][kl]);
            }
        }
        __syncthreads();
    }
#pragma unroll
    for (int i = 0; i < 4; ++i) {
        const int n = n0 + ty * 4 + i;
        float sv[4]; int si[4];
#pragma unroll
        for (int j = 0; j < 4; ++j) {
            const float* r = acc[i][j];
            float v = __fadd_rn(__fadd_rn(r[0], r[1]), __fadd_rn(r[2], r[3]));
            const int m = m0 + tx * 4 + j;
            if (n == m) v = __fsub_rn(v, 4.0f);
            if (m >= N_) v = -3.0e38f;
            sv[j] = v; si[j] = m;
        }
#pragma unroll
        for (int s = 0; s < 5; ++s) {
            const int pa_[5] = {0, 2, 0, 1, 1};
            const int pb_[5] = {1, 3, 2, 3, 2};
            const int a_ = pa_[s], b_ = pb_[s];
            const bool sw = (sv[b_] > sv[a_]) || (sv[b_] == sv[a_] && si[b_] < si[a_]);
            const float tv = sw ? sv[b_] : sv[a_]; const int ti = sw ? si[b_] : si[a_];
            sv[b_] = sw ? sv[a_] : sv[b_]; si[b_] = sw ? si[a_] : si[b_];
            sv[a_] = tv; si[a_] = ti;
        }
#pragma unroll
        for (int it = 0; it < 9; ++it) {
            float bv2 = sv[0]; int bi = si[0];
#pragma unroll
            for (int mk = 1; mk <= 8; mk <<= 1) {
                const float ov = __shfl_xor(bv2, mk, 64);
                const int  oi = __shfl_xor(bi, mk, 64);
                if (ov > bv2 || (ov == bv2 && oi < bi)) { bv2 = ov; bi = oi; }
            }
            if (si[0] == bi) {
                sv[0] = sv[1]; si[0] = si[1];
                sv[1] = sv[2]; si[1] = si[2];
                sv[2] = sv[3]; si[2] = si[3];
                sv[3] = -3.0e38f; si[3] = 0x7fffffff;
            }
            if (tx == 0 && n < N_) {
                const size_t o = ((size_t)b * N_ + n) * NC_ + blockIdx.y * 9 + it;
                cv[o] = bv2; ci[o] = bi;
            }
        }
    }
}

// --------------------------------------------------------------------------
__global__ __launch_bounds__(256) void merge_topk(
    const float* __restrict__ cv, const int* __restrict__ ci,
    int* __restrict__ nbidx) {
    const int row = blockIdx.x * 4 + (threadIdx.x >> 6);
    const int lane = threadIdx.x & 63;
    const size_t base = (size_t)row * NC_;
    float v0 = cv[base + lane]; int i0 = ci[base + lane];
    float v1 = -3.0e38f; int i1 = 0x7fffffff;
    if (lane + 64 < NC_) { v1 = cv[base + 64 + lane]; i1 = ci[base + 64 + lane]; }
#pragma unroll
    for (int it = 0; it < 9; ++it) {
        float bv = v0; int bi = i0;
        if (v1 > bv || (v1 == bv && i1 < bi)) { bv = v1; bi = i1; }
#pragma unroll
        for (int off = 32; off; off >>= 1) {
            const float ov = __shfl_xor(bv, off, 64);
            const int  oi = __shfl_xor(bi, off, 64);
            if (ov > bv || (ov == bv && oi < bi)) { bv = ov; bi = oi; }
        }
        if (i0 == bi) v0 = -3.0e38f;
        if (i1 == bi) v1 = -3.0e38f;
        if (lane == 0) nbidx[(size_t)row * 9 + it] = bi;
    }
}

// --------------------------------------------------------------------------
__global__ void gin_gather(const float* __restrict__ nf, const int* __restrict__ nbidx,
                           const float* __restrict__ w, const float* __restrict__ epsp,
                           bf16_t* __restrict__ outbf) {
    const int node = blockIdx.x;
    const int c = threadIdx.x;
    const int b = node / N_;
    const float* nfb = nf + (size_t)b * N_ * C_;
    const int nl = node - b * N_;
    float acc = (1.0f + epsp[0]) * nfb[(size_t)nl * C_ + c];
#pragma unroll
    for (int j = 0; j < 9; ++j) {
        const int ij = nbidx[(size_t)node * 9 + j];
        const float wj = w ? w[(size_t)node * 9 + j] : 1.0f;
        acc += wj * nfb[(size_t)ij * C_ + c];
    }
    outbf[(size_t)node * C_ + c] = (bf16_t)acc;
}

// --------------------------------------------------------------------------
// bf16 MFMA GEMM, 128-row tiles (r18)
// --------------------------------------------------------------------------
template <int ACT, bool ACCUM, bool WF32, bool WBF>
__global__ __launch_bounds__(256) void bgemm(
    const bf16_t* __restrict__ A, int lda, int ka,
    const bf16_t* __restrict__ WT, int ldwt,
    const float* __restrict__ bias, const float* __restrict__ bns,
    const float* __restrict__ bnt,
    float* __restrict__ Cf, bf16_t* __restrict__ Cb, int ldc) {
    const int wave = threadIdx.x >> 6, lane = threadIdx.x & 63;
    const int m0 = blockIdx.x * 128 + wave * 32;
    const int n0 = blockIdx.y * 64;
    const int csub = lane & 15;
    const int kslot = (lane >> 4) * 8;
    const bf16_t* ap0 = A + (size_t)(m0 + csub) * lda + kslot;
    const bf16_t* ap1 = A + (size_t)(m0 + 16 + csub) * lda + kslot;
    f32x4 acc[2][4];
#pragma unroll
    for (int mi = 0; mi < 2; ++mi)
#pragma unroll
        for (int c4 = 0; c4 < 4; ++c4) acc[mi][c4] = (f32x4){0.f, 0.f, 0.f, 0.f};
    const bf16_t* bp[4];
#pragma unroll
    for (int c4 = 0; c4 < 4; ++c4)
        bp[c4] = WT + (size_t)(n0 + c4 * 16 + csub) * ldwt + kslot;
    for (int k0 = 0; k0 < ka; k0 += 32) {
        const bf16x8 a0 = *(const bf16x8*)(ap0 + k0);
        const bf16x8 a1 = *(const bf16x8*)(ap1 + k0);
#pragma unroll
        for (int c4 = 0; c4 < 4; ++c4) {
            const bf16x8 bfrag = *(const bf16x8*)(bp[c4] + k0);
            acc[0][c4] = __builtin_amdgcn_mfma_f32_16x16x32_bf16(a0, bfrag, acc[0][c4], 0, 0, 0);
            acc[1][c4] = __builtin_amdgcn_mfma_f32_16x16x32_bf16(a1, bfrag, acc[1][c4], 0, 0, 0);
        }
    }
#pragma unroll
    for (int mi = 0; mi < 2; ++mi) {
        const int rbase = m0 + mi * 16 + (lane >> 4) * 4;
#pragma unroll
        for (int c4 = 0; c4 < 4; ++c4) {
            const int gcol = n0 + c4 * 16 + csub;
#pragma unroll
            for (int r = 0; r < 4; ++r) {
                const int grow = rbase + r;
                float z = acc[mi][c4][r];
                if (bias) z += bias[gcol];
                if (bns)  z = z * bns[gcol] + bnt[gcol];
                if (ACT == 1) z = fmaxf(z, 0.0f);
                if (ACT == 2) z = gelu_tanh(z);
                if (ACCUM) z += Cf[(size_t)grow * ldc + gcol];
                if (WF32) Cf[(size_t)grow * ldc + gcol] = z;
                if (WBF)  Cb[(size_t)grow * ldc + gcol] = (bf16_t)z;
            }
        }
    }
}

// --------------------------------------------------------------------------
// edge attention: one WAVE per node, eA read once (r18)
// --------------------------------------------------------------------------
__global__ __launch_bounds__(256) void edge_att_node(
    const float* __restrict__ eA, const float* __restrict__ eB,
    const int* __restrict__ nbidx, const float* __restrict__ w2,
    const float* __restrict__ b2p, float* __restrict__ out) {
    const int node = blockIdx.x * 4 + (threadIdx.x >> 6);
    const int lane = threadIdx.x & 63;
    const int b = node / N_;
    const float* pa = eA + (size_t)node * C_;
    const float* ebb = eB + (size_t)b * N_ * C_;
    int idx[9];
#pragma unroll
    for (int j = 0; j < 9; ++j) idx[j] = nbidx[(size_t)node * 9 + j];
    float s[9];
#pragma unroll
    for (int j = 0; j < 9; ++j) s[j] = 0.f;
#pragma unroll
    for (int t = 0; t < 6; ++t) {
        const int c = lane + 64 * t;
        const float a = pa[c];
        const float w = w2[c];
#pragma unroll
        for (int j = 0; j < 9; ++j)
            s[j] += fmaxf(a + ebb[(size_t)idx[j] * C_ + c], 0.f) * w;
    }
#pragma unroll
    for (int j = 0; j < 9; ++j)
#pragma unroll
        for (int off = 32; off; off >>= 1) s[j] += __shfl_xor(s[j], off, 64);
    if (lane < 9)
        out[(size_t)node * 9 + lane] =
            1.0f / (1.0f + expf(-(s[lane] + b2p[0])));
}

// --------------------------------------------------------------------------
__global__ __launch_bounds__(256) void ffn_final(
    const float* __restrict__ acc, const float* __restrict__ ne,
    const float* __restrict__ b2, const float* __restrict__ s2,
    const float* __restrict__ t2, float* __restrict__ out) {
    __shared__ float T[32][33];
    const int bb = blockIdx.z;
    const int n0 = blockIdx.x * 32, c0 = blockIdx.y * 32;
    const int tx = threadIdx.x, ty = threadIdx.y;
#pragma unroll
    for (int ii = 0; ii < 4; ++ii) {
        const int nl = ty + 8 * ii;
        const int n = n0 + nl, c = c0 + tx;
        float z = 0.f;
        if (n < N_) {
            const size_t o = ((size_t)bb * N_ + n) * C_ + c;
            z = (acc[o] + b2[c]) * s2[c] + t2[c] + ne[o];
        }
        T[nl][tx] = z;
    }
    __syncthreads();
#pragma unroll
    for (int ii = 0; ii < 4; ++ii) {
        const int cl = ty + 8 * ii;
        const int n = n0 + tx;
        if (n < N_) out[((size_t)bb * C_ + c0 + cl) * N_ + n] = T[tx][cl];
    }
}

// --------------------------------------------------------------------------
extern "C" void kernel_launch(void* const* d_in, const int* in_sizes, int n_in,
                              void* d_out, int out_size, void* d_ws, size_t ws_size,
                              hipStream_t stream) {
    (void)in_sizes; (void)n_in; (void)out_size; (void)ws_size;
    const float* x      = (const float*)d_in[0];
    const float* fc1_w  = (const float*)d_in[2];
    const float* fc1_b  = (const float*)d_in[3];
    const float* bn1_g  = (const float*)d_in[4];
    const float* bn1_b  = (const float*)d_in[5];
    const float* bn1_m  = (const float*)d_in[6];
    const float* bn1_v  = (const float*)d_in[7];
    const float* gineps = (const float*)d_in[8];
    const float* gin_w1 = (const float*)d_in[9];
    const float* gin_b1 = (const float*)d_in[10];
    const float* gin_w2 = (const float*)d_in[11];
    const float* gin_b2 = (const float*)d_in[12];
    const float* att_w1 = (const float*)d_in[13];
    const float* att_b1 = (const float*)d_in[14];
    const float* att_w2 = (const float*)d_in[15];
    const float* att_b2 = (const float*)d_in[16];
    const float* ffn_w1 = (const float*)d_in[17];
    const float* ffn_b1 = (const float*)d_in[18];
    const float* fbn1_g = (const float*)d_in[19];
    const float* fbn1_b = (const float*)d_in[20];
    const float* fbn1_m = (const float*)d_in[21];
    const float* fbn1_v = (const float*)d_in[22];
    const float* ffn_w2 = (const float*)d_in[23];
    const float* ffn_b2 = (const float*)d_in[24];
    const float* fbn2_g = (const float*)d_in[25];
    const float* fbn2_b = (const float*)d_in[26];
    const float* fbn2_m = (const float*)d_in[27];
    const float* fbn2_v = (const float*)d_in[28];

    float* outp = (float*)d_out;

    // ws pool: [P0 RC][P1 RC][P2 RC][nbidx E int][prep 4608][norms R_][WT bf16]
    float* P0 = (float*)d_ws;
    float* P1 = P0 + RC_;
    float* P2 = P0 + 2 * RC_;                 // NF lives here
    int*   nbidx = (int*)(P0 + 3 * RC_);
    float* prep  = (float*)(nbidx + E_);
    float* norms = prep + 4608;
    bf16_t* gw1T = (bf16_t*)(norms + R_);     // [768][384]
    bf16_t* gw2T = gw1T + 768 * 384;          // [384][768]
    bf16_t* fw1T = gw2T + 384 * 768;          // [1536][384]
    bf16_t* fw2T = fw1T + 1536 * 384;         // [384][1536]
    bf16_t* aw1Ttop = fw2T + 384 * 1536;      // [384][384]
    bf16_t* aw1Tbot = aw1Ttop + 384 * 384;    // [384][384]
    float* cv = P0;                           // R*117 floats
    int*   ci = (int*)(cv + (size_t)R_ * NC_);
    float* EMB = outp + E_;                   // out-1 region as scratch
    const float* pB1s = prep;
    const float* pF1s = prep + 768,  *pF1t = prep + 2304;
    const float* pF2s = prep + 3840, *pF2t = prep + 4224;

    const dim3 gf6(392, 6), gb6(392, 6), gb12(392, 12);

    prep_bn<<<6, 256, 0, stream>>>(bn1_g, bn1_v,
                                   fbn1_g, fbn1_b, fbn1_m, fbn1_v,
                                   fbn2_g, fbn2_b, fbn2_m, fbn2_v, prep);
    wconv_T<<<(768 * 384 + 255) / 256, 256, 0, stream>>>(gin_w1, gw1T, 384, 768);
    wconv_T<<<(384 * 768 + 255) / 256, 256, 0, stream>>>(gin_w2, gw2T, 768, 384);
    wconv_T<<<(1536 * 384 + 255) / 256, 256, 0, stream>>>(ffn_w1, fw1T, 384, 1536);
    wconv_T<<<(384 * 1536 + 255) / 256, 256, 0, stream>>>(ffn_w2, fw2T, 1536, 384);
    wconv_T<<<(384 * 384 + 255) / 256, 256, 0, stream>>>(att_w1, aw1Ttop, 384, 384);
    wconv_T<<<(384 * 384 + 255) / 256, 256, 0, stream>>>(att_w1 + (size_t)384 * 384,
                                                         aw1Tbot, 384, 384);

    // FROZEN nbidx chain: nf -> P2
    fc1_gemm<<<gf6, 256, 0, stream>>>(x, fc1_w, fc1_b, pB1s, bn1_m, bn1_b, P2);
    rownorm_np<<<R_ / 256, 256, 0, stream>>>(P2, norms);
    l2div<<<R_ / 4, 256, 0, stream>>>(P2, norms);
    sim_topk_np<<<dim3(NT_, NT_, B_), 256, 0, stream>>>(P2, cv, ci);
    merge_topk<<<R_ / 4, 256, 0, stream>>>(cv, ci, nbidx);

    // GIN1 (bf16): h1bf -> P0 lo (cv/ci dead); midbf -> P1; embbf -> P0 hi
    bf16_t* h1bf  = (bf16_t*)P0;
    bf16_t* midbf = (bf16_t*)P1;
    bf16_t* embbf = (bf16_t*)(P0 + RC_ / 2);
    gin_gather<<<R_, 384, 0, stream>>>(P2, nbidx, nullptr, gineps, h1bf);
    bgemm<1, false, false, true><<<gb12, 256, 0, stream>>>(
        h1bf, 384, 384, gw1T, 384, gin_b1, nullptr, nullptr,
        nullptr, midbf, 768);
    bgemm<0, false, false, true><<<gb6, 256, 0, stream>>>(
        midbf, 768, 768, gw2T, 768, gin_b2, nullptr, nullptr,
        nullptr, embbf, 384);

    // attention (bf16 gemms, f32 outputs): embA -> P1 (midbf dead), embB -> EMB
    bgemm<0, false, true, false><<<gb6, 256, 0, stream>>>(
        embbf, 384, 384, aw1Ttop, 384, att_b1, nullptr, nullptr,
        P1, nullptr, 384);
    bgemm<0, false, true, false><<<gb6, 256, 0, stream>>>(
        embbf, 384, 384, aw1Tbot, 384, nullptr, nullptr, nullptr,
        EMB, nullptr, 384);
    edge_att_node<<<R_ / 4, 256, 0, stream>>>(P1, EMB, nbidx, att_w2, att_b2, outp);

    // GIN2 (bf16): h2bf -> P0 lo; mid -> P1; ne f32 -> P0, nebf -> EMB
    bf16_t* h2bf = (bf16_t*)P0;
    bf16_t* nebf = (bf16_t*)EMB;
    gin_gather<<<R_, 384, 0, stream>>>(P2, nbidx, outp, gineps, h2bf);
    bgemm<1, false, false, true><<<gb12, 256, 0, stream>>>(
        h2bf, 384, 384, gw1T, 384, gin_b1, nullptr, nullptr,
        nullptr, (bf16_t*)P1, 768);
    bgemm<0, false, true, true><<<gb6, 256, 0, stream>>>(
        (bf16_t*)P1, 768, 768, gw2T, 768, gin_b2, nullptr, nullptr,
        P0, nebf, 384);

    // FFN (bf16, 2 K-chunks of 768): ybf -> P1; acc -> P2 (NF dead)
    bf16_t* ybf = (bf16_t*)P1;
    for (int g = 0; g < 2; ++g) {
        bgemm<2, false, false, true><<<gb12, 256, 0, stream>>>(
            nebf, 384, 384, fw1T + (size_t)g * 768 * 384, 384,
            ffn_b1 + g * 768, pF1s + g * 768, pF1t + g * 768,
            nullptr, ybf, 768);
        if (g == 0)
            bgemm<0, false, true, false><<<gb6, 256, 0, stream>>>(
                ybf, 768, 768, fw2T + (size_t)g * 768, 1536,
                nullptr, nullptr, nullptr, P2, nullptr, 384);
        else
            bgemm<0, true, true, false><<<gb6, 256, 0, stream>>>(
                ybf, 768, 768, fw2T + (size_t)g * 768, 1536,
                nullptr, nullptr, nullptr, P2, nullptr, 384);
    }

    // BN2 + residual + transpose (acc = P2, ne = P0) -> out-1
    ffn_final<<<dim3(25, 12, 64), dim3(32, 8), 0, stream>>>(P2, P0, ffn_b2,
                                                            pF2s, pF2t, outp + E_);
}